// Round 1
// 243.792 us; speedup vs baseline: 1.1077x; 1.1077x over previous
//
#include <hip/hip_runtime.h>

typedef unsigned short u16;
typedef unsigned int u32;
typedef __bf16 bf16x8 __attribute__((ext_vector_type(8)));
typedef float f32x4 __attribute__((ext_vector_type(4)));
typedef u16 u16x4 __attribute__((ext_vector_type(4)));
typedef __attribute__((address_space(1))) void* as1_t;
typedef __attribute__((address_space(3))) void* as3_t;

#define LOG2E 1.4426950408889634f
#define MFMA(a,b,c) __builtin_amdgcn_mfma_f32_16x16x32_bf16(a,b,c,0,0,0)

__device__ __forceinline__ u16 f2bf(float f){
  u32 u = __float_as_uint(f);
  return (u16)((u + 0x7FFFu + ((u >> 16) & 1u)) >> 16);
}
__device__ __forceinline__ float bf2f(u16 x){
  return __uint_as_float(((u32)x) << 16);
}
#if __has_builtin(__builtin_amdgcn_cvt_pk_bf16_f32)
__device__ __forceinline__ u16x4 pk4(float a, float b, float c, float d){
  auto lo = __builtin_amdgcn_cvt_pk_bf16_f32(a,b);
  auto hi = __builtin_amdgcn_cvt_pk_bf16_f32(c,d);
  union { u16x4 v; u32 w[2]; } u;
  u.w[0] = __builtin_bit_cast(u32, lo);
  u.w[1] = __builtin_bit_cast(u32, hi);
  return u.v;
}
#else
__device__ __forceinline__ u16x4 pk4(float a, float b, float c, float d){
  u16x4 r = { f2bf(a), f2bf(b), f2bf(c), f2bf(d) };
  return r;
}
#endif
__device__ __forceinline__ void gld16(const u16* gp, u16* lp){
  __builtin_amdgcn_global_load_lds((as1_t)(u16*)gp, (as3_t)lp, 16, 0, 0);
}

#define SBAR  __builtin_amdgcn_s_barrier()
#define SCHB  __builtin_amdgcn_sched_barrier(0)
#define SP1   __builtin_amdgcn_s_setprio(1)
#define SP0   __builtin_amdgcn_s_setprio(0)
#define WAITL0 asm volatile("s_waitcnt lgkmcnt(0)" ::: "memory")
#define WAITV2 asm volatile("s_waitcnt vmcnt(2)" ::: "memory")

// ---------------- prep: cast both inputs + all 5 weight transposes, ONE launch ----------------
__global__ void prep_kernel(const float* __restrict__ vis, u16* __restrict__ vis16,
                            const float* __restrict__ txt, u16* __restrict__ txt16,
                            const float* __restrict__ Wq, const float* __restrict__ Wk,
                            const float* __restrict__ Wv, const float* __restrict__ Wo,
                            u16* __restrict__ T0, u16* __restrict__ T1,
                            u16* __restrict__ T2, u16* __restrict__ T3,
                            u16* __restrict__ T4){
  int bid = blockIdx.x;
  if(bid < 8192){
    const float* src = (bid < 4096) ? vis : txt;
    u16* dst = (bid < 4096) ? vis16 : txt16;
    int idx = ((bid & 4095)*256 + threadIdx.x)*4;
    float4 v = *(const float4*)(src + idx);
    *(u16x4*)(dst + idx) = pk4(v.x, v.y, v.z, v.w);
    return;
  }
  int rr = bid - 8192;
  int wi = rr >> 8, tile = rr & 255;
  const float* W; u16* WT;
  switch(wi){
    case 0: W = Wq; WT = T0; break;
    case 1: W = Wv; WT = T1; break;
    case 2: W = Wk; WT = T2; break;
    case 3: W = Wv; WT = T3; break;
    default: W = Wo; WT = T4; break;
  }
  __shared__ u16 t[64][65];
  int bn = (tile & 15)*64, bk = (tile >> 4)*64;
  int c = threadIdx.x & 63, r0 = threadIdx.x >> 6;
  #pragma unroll
  for(int j=0;j<64;j+=4){
    int r = r0 + j;
    t[r][c] = f2bf(W[(bk + r)*1024 + bn + c]);
  }
  __syncthreads();
  #pragma unroll
  for(int j=0;j<64;j+=4){
    int r = r0 + j;
    WT[(bn + r)*1024 + bk + c] = t[c][r];
  }
}

// ---------------- merged projection GEMM: 256x256 tile, 8-phase pipelined schedule -----------
// (T2 XOR-swizzled LDS via pre-swizzled global src, T3/T4 counted vmcnt(2), T5 setprio)
// z=0: vis->[Q | V2^T], z=1: txt->[K | V^T]
// bn<1024 -> Cn [b][h][s][d] (normal); bn>=1024 -> Ct [b][h][d][s] (transposed, u16x4 stores)
__global__ __launch_bounds__(512, 2)
void proj_gemm_kernel(const u16* __restrict__ Avis, const u16* __restrict__ Atxt,
                      const u16* __restrict__ Wvis, const u16* __restrict__ Wtxt,
                      u16* __restrict__ Qb, u16* __restrict__ V2t,
                      u16* __restrict__ Kb, u16* __restrict__ Vt)
{
  const u16 *A, *Bt; u16 *Cn, *Ct;
  if(blockIdx.z == 0){ A = Avis; Bt = Wvis; Cn = Qb; Ct = V2t; }
  else               { A = Atxt; Bt = Wtxt; Cn = Kb; Ct = Vt;  }
  // 128 KiB: buf0 {A[256][64], B[256][64]}, buf1 same. u16 offsets:
  //   buf b: A at b*32768, B at b*32768 + 16384.
  __shared__ u16 lds[65536];
  const int tid = threadIdx.x, w = tid >> 6, lane = tid & 63;
  const int quad = lane >> 4, cl = lane & 15;
  const int wr = w >> 2, wc = w & 3;             // 2 m-waves x 4 n-waves, 128x64 per wave
  const int bm = blockIdx.y*256, bn = blockIdx.x*256;
  // swizzle: LDS[row][slot j] = global[row][j ^ (row&7)]  (16B slots, row&7 == cl&7)
  const int sx0 = ((quad    ) ^ (cl & 7)) << 3;  // kc=0 slot, u16 units
  const int sx1 = ((quad + 4) ^ (cl & 7)) << 3;  // kc=1 slot
  const int arow = ((wr << 7) + cl) << 6;        // A row base (u16): (wr*128+cl)*64
  const int brow = (((wc << 6) + cl) << 6) + 16384;

  f32x4 acc[8][4];
  #pragma unroll
  for(int a=0;a<8;a++)
    #pragma unroll
    for(int b=0;b<4;b++){ f32x4 z = {0.f,0.f,0.f,0.f}; acc[a][b] = z; }
  bf16x8 af[4][2], bf0[2][2], bf1[2][2];

  // stage one half-tile (128 rows x 64 K, 16 KiB) : 2 gld16 per thread, linear LDS dest,
  // swizzle applied on the GLOBAL source address (involution, rule #21).
#define STAGE(G, gbase, mo, h, kk) { \
    _Pragma("unroll") \
    for(int ii=0;ii<2;ii++){ \
      int slot_ = ii*512 + tid; int r_ = slot_ >> 3, cs_ = slot_ & 7; \
      gld16((G) + (size_t)((gbase) + (h)*128 + r_)*1024 + (kk) + ((cs_ ^ (r_ & 7)) << 3), \
            lds + (mo) + ((h)*1024 + ii*512 + (w << 6))*8); } }

#define LDA(bo, mh) { \
    _Pragma("unroll") \
    for(int q_=0;q_<4;q_++){ \
      int ro_ = arow + (((mh)*4+q_) << 10); \
      af[q_][0] = *(const bf16x8*)(lds + (bo) + ro_ + sx0); \
      af[q_][1] = *(const bf16x8*)(lds + (bo) + ro_ + sx1); } }

#define LDB(bo, nh, bfv) { \
    _Pragma("unroll") \
    for(int r2_=0;r2_<2;r2_++){ \
      int ro_ = brow + (((nh)*2+r2_) << 10); \
      bfv[r2_][0] = *(const bf16x8*)(lds + (bo) + ro_ + sx0); \
      bfv[r2_][1] = *(const bf16x8*)(lds + (bo) + ro_ + sx1); } }

#define MM(mh, bfv, nh) { \
    _Pragma("unroll") \
    for(int q_=0;q_<4;q_++) \
      _Pragma("unroll") \
      for(int r2_=0;r2_<2;r2_++){ \
        acc[(mh)*4+q_][(nh)*2+r2_] = MFMA(af[q_][0], bfv[r2_][0], acc[(mh)*4+q_][(nh)*2+r2_]); \
        acc[(mh)*4+q_][(nh)*2+r2_] = MFMA(af[q_][1], bfv[r2_][1], acc[(mh)*4+q_][(nh)*2+r2_]); } }

  // prologue: tile0 (buf0, 4 half-tiles) + tile1.A0 (buf1); wait tile0 (allow tile1.A0 in flight)
  STAGE(A , bm, 0,      0, 0); STAGE(A , bm, 0,      1, 0);
  STAGE(Bt, bn, 16384,  0, 0); STAGE(Bt, bn, 16384,  1, 0);
  STAGE(A , bm, 32768,  0, 64);
  WAITV2; SBAR;

  for(int i=0;i<8;i++){
    const int k0a = i*128, k0b = k0a + 64;
    const int ku = (i<7) ? k0a + 128 : k0a;   // tile 2i+2 (clamped: benign re-stage on last iter)
    const int kv = (i<7) ? k0b + 128 : k0b;   // tile 2i+3 (clamped)
    // ---- K-tile 2i from buf0 ----
    // P1: quadrant (mh0, nh0)
    LDA(0, 0); LDB(0, 0, bf0);
    STAGE(A , bm, 32768,        1, k0b);      // buf1.A1  (tile 2i+1)
    SBAR; WAITL0; SCHB;
    SP1; MM(0, bf0, 0); SP0;
    SBAR;
    // P2: quadrant (mh0, nh1)
    LDB(0, 1, bf1);
    STAGE(Bt, bn, 32768+16384,  0, k0b);      // buf1.B0
    SBAR; WAITL0; SCHB;
    SP1; MM(0, bf1, 1); SP0;
    SBAR;
    // P3: quadrant (mh1, nh1)
    LDA(0, 1);
    STAGE(Bt, bn, 32768+16384,  1, k0b);      // buf1.B1
    SBAR; WAITL0; SCHB;
    SP1; MM(1, bf1, 1); SP0;
    SBAR;
    // P4: quadrant (mh1, nh0); counted vmcnt -> tile 2i+1 fully in LDS
    STAGE(A , bm, 0,            0, ku);       // buf0.A0  (tile 2i+2)
    SBAR; WAITL0; SCHB;
    SP1; MM(1, bf0, 0); SP0;
    WAITV2;
    SBAR;
    // ---- K-tile 2i+1 from buf1 ----
    // P5
    LDA(32768, 0); LDB(32768, 0, bf0);
    STAGE(A , bm, 0,            1, ku);       // buf0.A1
    SBAR; WAITL0; SCHB;
    SP1; MM(0, bf0, 0); SP0;
    SBAR;
    // P6
    LDB(32768, 1, bf1);
    STAGE(Bt, bn, 16384,        0, ku);       // buf0.B0
    SBAR; WAITL0; SCHB;
    SP1; MM(0, bf1, 1); SP0;
    SBAR;
    // P7
    LDA(32768, 1);
    STAGE(Bt, bn, 16384,        1, ku);       // buf0.B1
    SBAR; WAITL0; SCHB;
    SP1; MM(1, bf1, 1); SP0;
    SBAR;
    // P8: counted vmcnt -> tile 2i+2 fully in LDS
    STAGE(A , bm, 32768,        0, kv);       // buf1.A0  (tile 2i+3)
    SBAR; WAITL0; SCHB;
    SP1; MM(1, bf0, 0); SP0;
    WAITV2;
    SBAR;
  }
#undef STAGE
#undef LDA
#undef LDB
#undef MM

  // epilogue: C-write (layouts identical to previous kernel)
  if(bn < 1024){
    #pragma unroll
    for(int mf=0; mf<8; mf++){
      int m0 = bm + wr*128 + mf*16 + quad*4;
      #pragma unroll
      for(int nf=0; nf<4; nf++){
        int n = bn + wc*64 + nf*16 + cl;
        int h = n >> 6, d = n & 63;
        #pragma unroll
        for(int i2=0;i2<4;i2++){
          int m = m0 + i2; int b = m >> 10, s = m & 1023;
          Cn[(((size_t)(b*16 + h)*1024 + s) << 6) + d] = f2bf(acc[mf][nf][i2]);
        }
      }
    }
  } else {
    #pragma unroll
    for(int mf=0; mf<8; mf++){
      int m0 = bm + wr*128 + mf*16 + quad*4;
      int b = m0 >> 10, s = m0 & 1023;
      #pragma unroll
      for(int nf=0; nf<4; nf++){
        int nn = bn - 1024 + wc*64 + nf*16 + cl;
        int h = nn >> 6, d = nn & 63;
        *(u16x4*)(Ct + (((size_t)(b*16 + h)*64 + d) << 10) + s) =
            pk4(acc[mf][nf][0], acc[mf][nf][1], acc[mf][nf][2], acc[mf][nf][3]);
      }
    }
  }
}

// ---------------- output GEMM: out[8192 x 1024] f32 = A[8192 x 1024] * WoT, BK=64 ----------------
__global__ __launch_bounds__(256, 2)
void out_gemm_kernel(const u16* __restrict__ A, const u16* __restrict__ Bt,
                     float* __restrict__ Cf)
{
  __shared__ u16 lds[16384];
  u16* Al = lds; u16* Bl = lds + 8192;
  const int tid = threadIdx.x, w = tid >> 6, lane = tid & 63;
  const int quad = lane >> 4, cl = lane & 15;
  const int bm = blockIdx.y*128, bn = blockIdx.x*128;
  const int wm = (w >> 1)*64, wn = (w & 1)*64;
  f32x4 acc[4][4];
  #pragma unroll
  for(int a=0;a<4;a++)
    #pragma unroll
    for(int b=0;b<4;b++){ f32x4 z = {0.f,0.f,0.f,0.f}; acc[a][b] = z; }

  for(int k0=0;k0<1024;k0+=64){
    __syncthreads();
    #pragma unroll
    for(int i=0;i<4;i++){
      int slot = (w*4+i)*64 + lane;
      int c = slot >> 7, r = slot & 127;
      gld16(A  + (size_t)(bm + r)*1024 + k0 + c*8, Al + (w*4+i)*512);
      gld16(Bt + (size_t)(bn + r)*1024 + k0 + c*8, Bl + (w*4+i)*512);
    }
    __syncthreads();
    bf16x8 af[4][2], bfv[4][2];
    #pragma unroll
    for(int mt=0;mt<4;mt++)
      #pragma unroll
      for(int kc=0;kc<2;kc++)
        af[mt][kc] = *(const bf16x8*)(Al + (((kc*4+quad)*128) + wm + mt*16 + cl)*8);
    #pragma unroll
    for(int nt=0;nt<4;nt++)
      #pragma unroll
      for(int kc=0;kc<2;kc++)
        bfv[nt][kc] = *(const bf16x8*)(Bl + (((kc*4+quad)*128) + wn + nt*16 + cl)*8);
    #pragma unroll
    for(int mt=0;mt<4;mt++)
      #pragma unroll
      for(int nt=0;nt<4;nt++)
        #pragma unroll
        for(int kc=0;kc<2;kc++)
          acc[mt][nt] = MFMA(af[mt][kc], bfv[nt][kc], acc[mt][nt]);
  }
  #pragma unroll
  for(int mt=0;mt<4;mt++)
    #pragma unroll
    for(int nt=0;nt<4;nt++)
      #pragma unroll
      for(int i=0;i<4;i++){
        int m = bm + wm + mt*16 + quad*4 + i;
        int n = bn + wn + nt*16 + cl;
        Cf[(size_t)m*1024 + n] = acc[mt][nt][i];
      }
}

// ---------------- attention (vis): 8 waves x 16 q-rows; grid x=bh (XCD-grouped K/V) ----------------
__global__ __launch_bounds__(512, 4)
void attn_vis_kernel(const u16* __restrict__ Q, const u16* __restrict__ Kc,
                     const u16* __restrict__ Vt, u16* __restrict__ visA,
                     float* __restrict__ rl_g)
{
  __shared__ u16 lds[17408];   // 34816 B
  u16* Pl  = lds;              // P[q=128][72]; Q staged here first ([c8][128][8]=8192)
  u16* Kst = lds + 9216;       // [c8][64][8] = 4096 u16
  u16* Vst = lds + 13312;      // [d=64][ch^][8] swizzled = 4096 u16
  const int tid = threadIdx.x, w = tid>>6, lane = tid&63;
  const int quad = lane>>4, cl = lane&15;
  const int bh = blockIdx.x, q0 = blockIdx.y*128;   // XCD = bh % 8
  const u16* Qh  = Q  + (size_t)bh*65536;
  const u16* Kh  = Kc + (size_t)bh*65536;
  const u16* Vth = Vt + (size_t)bh*65536;

  #pragma unroll
  for(int i=0;i<2;i++){
    int slot = i*512 + tid;
    int c = slot >> 7, r = slot & 127;
    gld16(Qh + (size_t)(q0 + r)*64 + c*8, Pl + slot*8);
  }
  __syncthreads();
  bf16x8 qf[2];
  #pragma unroll
  for(int kk=0;kk<2;kk++)
    qf[kk] = *(const bf16x8*)(Pl + ((kk*4+quad)*128 + w*16 + cl)*8);
  __syncthreads();   // Pl now becomes the P buffer

  float lrun = 0.f;
  f32x4 oacc[4];
  #pragma unroll
  for(int dt=0;dt<4;dt++){ f32x4 z = {0.f,0.f,0.f,0.f}; oacc[dt] = z; }

  for(int kt=0;kt<16;kt++){
    __syncthreads();
    {
      int slot = tid;
      { int c = slot >> 6, r = slot & 63;
        gld16(Kh + (size_t)(kt*64 + r)*64 + c*8, Kst + slot*8); }
      { int d = slot >> 3, ch = slot & 7;
        gld16(Vth + (size_t)d*1024 + kt*64 + (ch^(d&7))*8, Vst + slot*8); }
    }
    __syncthreads();
    #pragma unroll
    for(int mtk=0;mtk<4;mtk++){
      f32x4 s = {0.f,0.f,0.f,0.f};
      #pragma unroll
      for(int kk=0;kk<2;kk++){
        bf16x8 ka = *(const bf16x8*)(Kst + ((kk*4+quad)*64 + mtk*16 + cl)*8);
        s = MFMA(ka, qf[kk], s);
      }
      float p0 = __builtin_amdgcn_exp2f(s[0]*LOG2E);
      float p1 = __builtin_amdgcn_exp2f(s[1]*LOG2E);
      float p2 = __builtin_amdgcn_exp2f(s[2]*LOG2E);
      float p3 = __builtin_amdgcn_exp2f(s[3]*LOG2E);
      lrun += (p0+p1)+(p2+p3);
      *(u16x4*)(Pl + (w*16 + cl)*72 + mtk*16 + quad*4) = pk4(p0,p1,p2,p3);
    }
    bf16x8 pa[2];
    #pragma unroll
    for(int kk=0;kk<2;kk++)
      pa[kk] = *(const bf16x8*)(Pl + (w*16 + cl)*72 + kk*32 + quad*8);
    #pragma unroll
    for(int dt=0;dt<4;dt++){
      int d = dt*16 + cl;
      #pragma unroll
      for(int kk=0;kk<2;kk++){
        bf16x8 vb = *(const bf16x8*)(Vst + d*64 + (((kk*4+quad)^(d&7))*8));
        oacc[dt] = MFMA(pa[kk], vb, oacc[dt]);
      }
    }
  }
  lrun += __shfl_xor(lrun, 16, 64);
  lrun += __shfl_xor(lrun, 32, 64);
  float rl = 1.f/lrun;
  if(quad == 0) rl_g[bh*1024 + q0 + w*16 + cl] = rl;
  const int b = bh >> 4, h = bh & 15;
  #pragma unroll
  for(int i=0;i<4;i++){
    float rr = __shfl(rl, quad*4 + i, 16);
    int q = q0 + w*16 + quad*4 + i;
    #pragma unroll
    for(int dt=0;dt<4;dt++)
      visA[(size_t)(b*1024 + q)*1024 + h*64 + dt*16 + cl] = f2bf(oacc[dt][i]*rr);
  }
}

// ---------------- attention (txt): 8 waves x 16 k-rows; grid x=bh; rl applied in-kernel ----------
__global__ __launch_bounds__(512, 4)
void attn_txt_kernel(const u16* __restrict__ Kc, const u16* __restrict__ Q,
                     const u16* __restrict__ V2t, const float* __restrict__ rl_g,
                     u16* __restrict__ txtA)
{
  __shared__ u16 lds[17408];
  u16* Pl  = lds;              // P^T[k=128][72]; K-block staged here first
  u16* Qst = lds + 9216;       // [c8][64][8]
  u16* Vst = lds + 13312;      // [d][ch^][8] swizzled (contraction = q)
  const int tid = threadIdx.x, w = tid>>6, lane = tid&63;
  const int quad = lane>>4, cl = lane&15;
  const int bh = blockIdx.x, k0 = blockIdx.y*128;   // XCD = bh % 8
  const u16* Kh  = Kc  + (size_t)bh*65536;
  const u16* Qh  = Q   + (size_t)bh*65536;
  const u16* Vth = V2t + (size_t)bh*65536;

  #pragma unroll
  for(int i=0;i<2;i++){
    int slot = i*512 + tid;
    int c = slot >> 7, r = slot & 127;
    gld16(Kh + (size_t)(k0 + r)*64 + c*8, Pl + slot*8);
  }
  __syncthreads();
  bf16x8 kb[2];
  #pragma unroll
  for(int kk=0;kk<2;kk++)
    kb[kk] = *(const bf16x8*)(Pl + ((kk*4+quad)*128 + w*16 + cl)*8);
  __syncthreads();

  f32x4 oacc[4];
  #pragma unroll
  for(int dt=0;dt<4;dt++){ f32x4 z = {0.f,0.f,0.f,0.f}; oacc[dt] = z; }

  for(int qt=0;qt<16;qt++){
    __syncthreads();
    {
      int slot = tid;
      { int c = slot >> 6, r = slot & 63;
        gld16(Qh + (size_t)(qt*64 + r)*64 + c*8, Qst + slot*8); }
      { int d = slot >> 3, ch = slot & 7;
        gld16(Vth + (size_t)d*1024 + qt*64 + (ch^(d&7))*8, Vst + slot*8); }
    }
    __syncthreads();
    f32x4 rv[4];
    #pragma unroll
    for(int mtq=0;mtq<4;mtq++)
      rv[mtq] = *(const f32x4*)(rl_g + bh*1024 + qt*64 + mtq*16 + quad*4);
    #pragma unroll
    for(int mtq=0;mtq<4;mtq++){
      f32x4 s = {0.f,0.f,0.f,0.f};
      #pragma unroll
      for(int kk=0;kk<2;kk++){
        bf16x8 qa = *(const bf16x8*)(Qst + ((kk*4+quad)*64 + mtq*16 + cl)*8);
        s = MFMA(qa, kb[kk], s);
      }
      float p0 = __builtin_amdgcn_exp2f(s[0]*LOG2E)*rv[mtq][0];
      float p1 = __builtin_amdgcn_exp2f(s[1]*LOG2E)*rv[mtq][1];
      float p2 = __builtin_amdgcn_exp2f(s[2]*LOG2E)*rv[mtq][2];
      float p3 = __builtin_amdgcn_exp2f(s[3]*LOG2E)*rv[mtq][3];
      *(u16x4*)(Pl + (w*16 + cl)*72 + mtq*16 + quad*4) = pk4(p0,p1,p2,p3);
    }
    bf16x8 pa[2];
    #pragma unroll
    for(int kk=0;kk<2;kk++)
      pa[kk] = *(const bf16x8*)(Pl + (w*16 + cl)*72 + kk*32 + quad*8);
    #pragma unroll
    for(int dt=0;dt<4;dt++){
      int d = dt*16 + cl;
      #pragma unroll
      for(int kk=0;kk<2;kk++){
        bf16x8 vb = *(const bf16x8*)(Vst + d*64 + (((kk*4+quad)^(d&7))*8));
        oacc[dt] = MFMA(pa[kk], vb, oacc[dt]);
      }
    }
  }
  const int b = bh >> 4, h = bh & 15;
  #pragma unroll
  for(int i=0;i<4;i++){
    int k = k0 + w*16 + quad*4 + i;
    #pragma unroll
    for(int dt=0;dt<4;dt++)
      txtA[(size_t)(b*1024 + k)*1024 + h*64 + dt*16 + cl] = f2bf(oacc[dt][i]);
  }
}

extern "C" void kernel_launch(void* const* d_in, const int* in_sizes, int n_in,
                              void* d_out, int out_size, void* d_ws, size_t ws_size,
                              hipStream_t stream)
{
  const float* vis = (const float*)d_in[0];
  const float* txt = (const float*)d_in[1];
  const float* Wq  = (const float*)d_in[2];
  const float* Wk  = (const float*)d_in[3];
  const float* Wv  = (const float*)d_in[4];
  const float* Wo  = (const float*)d_in[5];
  float* out = (float*)d_out;

  char* ws = (char*)d_ws;
  const size_t MB = 1u << 20;
  u16* vis16 = (u16*)(ws + 0);           // later: visA
  u16* txt16 = (u16*)(ws + 8*MB);        // later: txtA (contiguous with visA for out GEMM)
  u16* Wvis  = (u16*)(ws + 16*MB);       // [WqT | WvT]
  u16* Wtxt  = (u16*)(ws + 20*MB);       // [WkT | WvT]
  u16* Qb    = (u16*)(ws + 24*MB);
  u16* Kb    = (u16*)(ws + 32*MB);
  u16* Vt    = (u16*)(ws + 40*MB);       // V^T  [b][h][d][s]  (from txt proj)
  u16* V2t   = (u16*)(ws + 48*MB);       // V2^T [b][h][d][s]  (from vis proj)
  float* rl_g = (float*)(ws + 56*MB);
  u16* WoT   = (u16*)(ws + 57*MB);
  u16* visA = vis16;  u16* txtA = txt16;

  // 1: cast both inputs + 5 weight transposes
  prep_kernel<<<9472, 256, 0, stream>>>(vis, vis16, txt, txt16,
                                        Wq, Wk, Wv, Wo,
                                        Wvis, Wvis + 1048576, Wtxt, Wtxt + 1048576, WoT);
  // 2: merged projections, 256x256 tiles, 8-phase pipelined; V/V2 written pre-transposed
  proj_gemm_kernel<<<dim3(8,16,2), 512, 0, stream>>>(vis16, txt16, Wvis, Wtxt,
                                                     Qb, V2t, Kb, Vt);
  // 3: attention vis (produces rl); visA overwrites vis16 (dead after projections)
  attn_vis_kernel<<<dim3(64,8), 512, 0, stream>>>(Qb, Kb, Vt, visA, rl_g);
  // 4: attention txt (applies rl in-kernel); txtA overwrites txt16
  attn_txt_kernel<<<dim3(64,8), 512, 0, stream>>>(Kb, Qb, V2t, rl_g, txtA);
  // 5: merged output projection: M=8192 over visA||txtA (contiguous), f32 out
  out_gemm_kernel<<<dim3(8,64), 256, 0, stream>>>(visA, WoT, out);
}

// Round 2
// 226.889 us; speedup vs baseline: 1.1902x; 1.0745x over previous
//
#include <hip/hip_runtime.h>

typedef unsigned short u16;
typedef unsigned int u32;
typedef __bf16 bf16x8 __attribute__((ext_vector_type(8)));
typedef float f32x4 __attribute__((ext_vector_type(4)));
typedef u16 u16x4 __attribute__((ext_vector_type(4)));
typedef __attribute__((address_space(1))) void* as1_t;
typedef __attribute__((address_space(3))) void* as3_t;

#define LOG2E 1.4426950408889634f
#define MFMA(a,b,c) __builtin_amdgcn_mfma_f32_16x16x32_bf16(a,b,c,0,0,0)

__device__ __forceinline__ u16 f2bf(float f){
  u32 u = __float_as_uint(f);
  return (u16)((u + 0x7FFFu + ((u >> 16) & 1u)) >> 16);
}
__device__ __forceinline__ float bf2f(u16 x){
  return __uint_as_float(((u32)x) << 16);
}
#if __has_builtin(__builtin_amdgcn_cvt_pk_bf16_f32)
__device__ __forceinline__ u16x4 pk4(float a, float b, float c, float d){
  auto lo = __builtin_amdgcn_cvt_pk_bf16_f32(a,b);
  auto hi = __builtin_amdgcn_cvt_pk_bf16_f32(c,d);
  union { u16x4 v; u32 w[2]; } u;
  u.w[0] = __builtin_bit_cast(u32, lo);
  u.w[1] = __builtin_bit_cast(u32, hi);
  return u.v;
}
#else
__device__ __forceinline__ u16x4 pk4(float a, float b, float c, float d){
  u16x4 r = { f2bf(a), f2bf(b), f2bf(c), f2bf(d) };
  return r;
}
#endif
__device__ __forceinline__ void gld16(const u16* gp, u16* lp){
  __builtin_amdgcn_global_load_lds((as1_t)(u16*)gp, (as3_t)lp, 16, 0, 0);
}

#define SBAR  __builtin_amdgcn_s_barrier()
#define SCHB  __builtin_amdgcn_sched_barrier(0)
#define SP1   __builtin_amdgcn_s_setprio(1)
#define SP0   __builtin_amdgcn_s_setprio(0)
#define WAITL0 asm volatile("s_waitcnt lgkmcnt(0)" ::: "memory")
#define WAITV6 asm volatile("s_waitcnt vmcnt(6)" ::: "memory")

// ---------------- prep: cast both inputs + all 5 weight transposes, ONE launch ----------------
__global__ void prep_kernel(const float* __restrict__ vis, u16* __restrict__ vis16,
                            const float* __restrict__ txt, u16* __restrict__ txt16,
                            const float* __restrict__ Wq, const float* __restrict__ Wk,
                            const float* __restrict__ Wv, const float* __restrict__ Wo,
                            u16* __restrict__ T0, u16* __restrict__ T1,
                            u16* __restrict__ T2, u16* __restrict__ T3,
                            u16* __restrict__ T4){
  int bid = blockIdx.x;
  if(bid < 8192){
    const float* src = (bid < 4096) ? vis : txt;
    u16* dst = (bid < 4096) ? vis16 : txt16;
    int idx = ((bid & 4095)*256 + threadIdx.x)*4;
    float4 v = *(const float4*)(src + idx);
    *(u16x4*)(dst + idx) = pk4(v.x, v.y, v.z, v.w);
    return;
  }
  int rr = bid - 8192;
  int wi = rr >> 8, tile = rr & 255;
  const float* W; u16* WT;
  switch(wi){
    case 0: W = Wq; WT = T0; break;
    case 1: W = Wv; WT = T1; break;
    case 2: W = Wk; WT = T2; break;
    case 3: W = Wv; WT = T3; break;
    default: W = Wo; WT = T4; break;
  }
  __shared__ u16 t[64][65];
  int bn = (tile & 15)*64, bk = (tile >> 4)*64;
  int c = threadIdx.x & 63, r0 = threadIdx.x >> 6;
  #pragma unroll
  for(int j=0;j<64;j+=4){
    int r = r0 + j;
    t[r][c] = f2bf(W[(bk + r)*1024 + bn + c]);
  }
  __syncthreads();
  #pragma unroll
  for(int j=0;j<64;j+=4){
    int r = r0 + j;
    WT[(bn + r)*1024 + bk + c] = t[c][r];
  }
}

// ============ shared 256x128 (BK=64) 3-deep pipelined GEMM body =====================
// 8 waves, 4M x 2N split (64x64 per wave). LDS: 3 bufs x {A 256x64, B 128x64} = 144 KiB.
// 2 phases per K-tile, stage tile t+2 during tile t (3 half-tiles), vmcnt(6) once/tile.
// LDS XOR-swizzle: 16B slot j of row r holds global column slot j^(r&7); reads use
// sx = (chunk ^ (cl&7))*8 (rows always have row&7 == cl&7).
__device__ __forceinline__ void gemm_pipe(const u16* __restrict__ A,
                                          const u16* __restrict__ Bt,
                                          int bm, int bn,
                                          u16* __restrict__ lds,
                                          f32x4 (&acc)[4][4],
                                          int tid, int w, int quad, int cl,
                                          int wr, int wc)
{
  const int sx0 = ((quad    ) ^ (cl & 7)) << 3;      // kc=0 slot offset (u16)
  const int sx1 = ((quad + 4) ^ (cl & 7)) << 3;      // kc=1
  const int arow = ((wr << 6) + cl) << 6;            // (wr*64 + cl)*64
  const int brow = (((wc << 6) + cl) << 6) + 16384;  // (wc*64 + cl)*64 + Boff
  bf16x8 af[4][2], bfv[2][2];

#define STAGE128(G, gbase, dsto, kk) { \
    _Pragma("unroll") \
    for(int ii=0;ii<2;ii++){ \
      int slot_ = ii*512 + tid; int r_ = slot_ >> 3, cs_ = slot_ & 7; \
      gld16((G) + (size_t)((gbase) + r_)*1024 + (kk) + ((cs_ ^ (r_ & 7)) << 3), \
            lds + (dsto) + (ii*512 + (w << 6))*8); } }

#define LDA_(bo) { \
    _Pragma("unroll") \
    for(int m_=0;m_<4;m_++){ \
      int ro_ = (bo) + arow + (m_ << 10); \
      af[m_][0] = *(const bf16x8*)(lds + ro_ + sx0); \
      af[m_][1] = *(const bf16x8*)(lds + ro_ + sx1); } }

#define LDB_(bo, nh) { \
    _Pragma("unroll") \
    for(int j_=0;j_<2;j_++){ \
      int ro_ = (bo) + brow + (((nh)*2 + j_) << 10); \
      bfv[j_][0] = *(const bf16x8*)(lds + ro_ + sx0); \
      bfv[j_][1] = *(const bf16x8*)(lds + ro_ + sx1); } }

#define MM_(nh) { \
    _Pragma("unroll") \
    for(int m_=0;m_<4;m_++) \
      _Pragma("unroll") \
      for(int j_=0;j_<2;j_++){ \
        acc[m_][(nh)*2+j_] = MFMA(af[m_][0], bfv[j_][0], acc[m_][(nh)*2+j_]); \
        acc[m_][(nh)*2+j_] = MFMA(af[m_][1], bfv[j_][1], acc[m_][(nh)*2+j_]); } }

  // prologue: tiles 0 (buf0) and 1 (buf1) fully staged; drain tile0, keep tile1 in flight
  STAGE128(A , bm      , 0,          0);
  STAGE128(A , bm + 128, 8192,       0);
  STAGE128(Bt, bn      , 16384,      0);
  STAGE128(A , bm      , 24576,      64);
  STAGE128(A , bm + 128, 24576+8192, 64);
  STAGE128(Bt, bn      , 24576+16384,64);
  WAITV6; SBAR;

  #pragma unroll
  for(int t=0;t<16;t++){
    const int c  = (t % 3) * 24576;
    const int n2 = ((t+2) % 3) * 24576;         // buffer of tile t-1 (all reads done)
    const int ts = ((t+2) & 15) << 6;           // k-offset of tile t+2 (clamped: dead restage)
    // phase 0: all A frags + B half 0; stage A(t+2)
    LDA_(c); LDB_(c, 0);
    STAGE128(A, bm      , n2,        ts);
    STAGE128(A, bm + 128, n2 + 8192, ts);
    SBAR; WAITL0; SCHB;
    SP1; MM_(0); SP0;
    SBAR;
    // phase 1: B half 1; stage B(t+2); counted vmcnt drains tile t+1 (issued 2 tiles ago)
    LDB_(c, 1);
    STAGE128(Bt, bn, n2 + 16384, ts);
    SBAR; WAITL0; SCHB;
    SP1; MM_(1); SP0;
    WAITV6;
    SBAR;
  }
#undef STAGE128
#undef LDA_
#undef LDB_
#undef MM_
}

// ---------------- merged projection GEMM: 256x128 tile, 3-deep pipeline ----------------------
// grid (16 m, 16 n, 2 z): bid%8 = m%8 -> A-panel sharers co-located per XCD.
// z=0: vis->[Q | V2^T], z=1: txt->[K | V^T]
__global__ __launch_bounds__(512, 2)
void proj_gemm_kernel(const u16* __restrict__ Avis, const u16* __restrict__ Atxt,
                      const u16* __restrict__ Wvis, const u16* __restrict__ Wtxt,
                      u16* __restrict__ Qb, u16* __restrict__ V2t,
                      u16* __restrict__ Kb, u16* __restrict__ Vt)
{
  const u16 *A, *Bt; u16 *Cn, *Ct;
  if(blockIdx.z == 0){ A = Avis; Bt = Wvis; Cn = Qb; Ct = V2t; }
  else               { A = Atxt; Bt = Wtxt; Cn = Kb; Ct = Vt;  }
  __shared__ u16 lds[73728];
  const int tid = threadIdx.x, w = tid >> 6, lane = tid & 63;
  const int quad = lane >> 4, cl = lane & 15;
  const int wr = w >> 1, wc = w & 1;
  const int bm = blockIdx.x*256, bn = blockIdx.y*128;

  f32x4 acc[4][4];
  #pragma unroll
  for(int a=0;a<4;a++)
    #pragma unroll
    for(int b=0;b<4;b++){ f32x4 z = {0.f,0.f,0.f,0.f}; acc[a][b] = z; }

  gemm_pipe(A, Bt, bm, bn, lds, acc, tid, w, quad, cl, wr, wc);

  if(bn < 1024){
    #pragma unroll
    for(int mf=0; mf<4; mf++){
      int m0 = bm + wr*64 + mf*16 + quad*4;
      #pragma unroll
      for(int nf=0; nf<4; nf++){
        int n = bn + wc*64 + nf*16 + cl;
        int h = n >> 6, d = n & 63;
        #pragma unroll
        for(int i2=0;i2<4;i2++){
          int m = m0 + i2; int b = m >> 10, s = m & 1023;
          Cn[(((size_t)(b*16 + h)*1024 + s) << 6) + d] = f2bf(acc[mf][nf][i2]);
        }
      }
    }
  } else {
    #pragma unroll
    for(int mf=0; mf<4; mf++){
      int m0 = bm + wr*64 + mf*16 + quad*4;
      int b = m0 >> 10, s = m0 & 1023;
      #pragma unroll
      for(int nf=0; nf<4; nf++){
        int nn = bn - 1024 + wc*64 + nf*16 + cl;
        int h = nn >> 6, d = nn & 63;
        *(u16x4*)(Ct + (((size_t)(b*16 + h)*64 + d) << 10) + s) =
            pk4(acc[mf][nf][0], acc[mf][nf][1], acc[mf][nf][2], acc[mf][nf][3]);
      }
    }
  }
}

// ---------------- output GEMM: out[8192 x 1024] f32 = A * WoT, 256x128 3-deep pipeline -------
// grid (32 m, 8 n): bid%8 = m%8 -> A-panel sharers co-located per XCD.
__global__ __launch_bounds__(512, 2)
void out_gemm_kernel(const u16* __restrict__ A, const u16* __restrict__ Bt,
                     float* __restrict__ Cf)
{
  __shared__ u16 lds[73728];
  const int tid = threadIdx.x, w = tid >> 6, lane = tid & 63;
  const int quad = lane >> 4, cl = lane & 15;
  const int wr = w >> 1, wc = w & 1;
  const int bm = blockIdx.x*256, bn = blockIdx.y*128;

  f32x4 acc[4][4];
  #pragma unroll
  for(int a=0;a<4;a++)
    #pragma unroll
    for(int b=0;b<4;b++){ f32x4 z = {0.f,0.f,0.f,0.f}; acc[a][b] = z; }

  gemm_pipe(A, Bt, bm, bn, lds, acc, tid, w, quad, cl, wr, wc);

  #pragma unroll
  for(int mf=0; mf<4; mf++)
    #pragma unroll
    for(int nf=0; nf<4; nf++)
      #pragma unroll
      for(int i=0;i<4;i++){
        int m = bm + wr*64 + mf*16 + quad*4 + i;
        int n = bn + wc*64 + nf*16 + cl;
        Cf[(size_t)m*1024 + n] = acc[mf][nf][i];
      }
}

// ---------------- attention (vis): 8 waves x 16 q-rows; grid x=bh (XCD-grouped K/V) ----------------
__global__ __launch_bounds__(512, 4)
void attn_vis_kernel(const u16* __restrict__ Q, const u16* __restrict__ Kc,
                     const u16* __restrict__ Vt, u16* __restrict__ visA,
                     float* __restrict__ rl_g)
{
  __shared__ u16 lds[17408];   // 34816 B
  u16* Pl  = lds;              // P[q=128][72]; Q staged here first ([c8][128][8]=8192)
  u16* Kst = lds + 9216;       // [c8][64][8] = 4096 u16
  u16* Vst = lds + 13312;      // [d=64][ch^][8] swizzled = 4096 u16
  const int tid = threadIdx.x, w = tid>>6, lane = tid&63;
  const int quad = lane>>4, cl = lane&15;
  const int bh = blockIdx.x, q0 = blockIdx.y*128;   // XCD = bh % 8
  const u16* Qh  = Q  + (size_t)bh*65536;
  const u16* Kh  = Kc + (size_t)bh*65536;
  const u16* Vth = Vt + (size_t)bh*65536;

  #pragma unroll
  for(int i=0;i<2;i++){
    int slot = i*512 + tid;
    int c = slot >> 7, r = slot & 127;
    gld16(Qh + (size_t)(q0 + r)*64 + c*8, Pl + slot*8);
  }
  __syncthreads();
  bf16x8 qf[2];
  #pragma unroll
  for(int kk=0;kk<2;kk++)
    qf[kk] = *(const bf16x8*)(Pl + ((kk*4+quad)*128 + w*16 + cl)*8);
  __syncthreads();   // Pl now becomes the P buffer

  float lrun = 0.f;
  f32x4 oacc[4];
  #pragma unroll
  for(int dt=0;dt<4;dt++){ f32x4 z = {0.f,0.f,0.f,0.f}; oacc[dt] = z; }

  for(int kt=0;kt<16;kt++){
    __syncthreads();
    {
      int slot = tid;
      { int c = slot >> 6, r = slot & 63;
        gld16(Kh + (size_t)(kt*64 + r)*64 + c*8, Kst + slot*8); }
      { int d = slot >> 3, ch = slot & 7;
        gld16(Vth + (size_t)d*1024 + kt*64 + (ch^(d&7))*8, Vst + slot*8); }
    }
    __syncthreads();
    #pragma unroll
    for(int mtk=0;mtk<4;mtk++){
      f32x4 s = {0.f,0.f,0.f,0.f};
      #pragma unroll
      for(int kk=0;kk<2;kk++){
        bf16x8 ka = *(const bf16x8*)(Kst + ((kk*4+quad)*64 + mtk*16 + cl)*8);
        s = MFMA(ka, qf[kk], s);
      }
      float p0 = __builtin_amdgcn_exp2f(s[0]*LOG2E);
      float p1 = __builtin_amdgcn_exp2f(s[1]*LOG2E);
      float p2 = __builtin_amdgcn_exp2f(s[2]*LOG2E);
      float p3 = __builtin_amdgcn_exp2f(s[3]*LOG2E);
      lrun += (p0+p1)+(p2+p3);
      *(u16x4*)(Pl + (w*16 + cl)*72 + mtk*16 + quad*4) = pk4(p0,p1,p2,p3);
    }
    bf16x8 pa[2];
    #pragma unroll
    for(int kk=0;kk<2;kk++)
      pa[kk] = *(const bf16x8*)(Pl + (w*16 + cl)*72 + kk*32 + quad*8);
    #pragma unroll
    for(int dt=0;dt<4;dt++){
      int d = dt*16 + cl;
      #pragma unroll
      for(int kk=0;kk<2;kk++){
        bf16x8 vb = *(const bf16x8*)(Vst + d*64 + (((kk*4+quad)^(d&7))*8));
        oacc[dt] = MFMA(pa[kk], vb, oacc[dt]);
      }
    }
  }
  lrun += __shfl_xor(lrun, 16, 64);
  lrun += __shfl_xor(lrun, 32, 64);
  float rl = 1.f/lrun;
  if(quad == 0) rl_g[bh*1024 + q0 + w*16 + cl] = rl;
  const int b = bh >> 4, h = bh & 15;
  #pragma unroll
  for(int i=0;i<4;i++){
    float rr = __shfl(rl, quad*4 + i, 16);
    int q = q0 + w*16 + quad*4 + i;
    #pragma unroll
    for(int dt=0;dt<4;dt++)
      visA[(size_t)(b*1024 + q)*1024 + h*64 + dt*16 + cl] = f2bf(oacc[dt][i]*rr);
  }
}

// ---------------- attention (txt): 8 waves x 16 k-rows; grid x=bh; rl applied in-kernel ----------
__global__ __launch_bounds__(512, 4)
void attn_txt_kernel(const u16* __restrict__ Kc, const u16* __restrict__ Q,
                     const u16* __restrict__ V2t, const float* __restrict__ rl_g,
                     u16* __restrict__ txtA)
{
  __shared__ u16 lds[17408];
  u16* Pl  = lds;              // P^T[k=128][72]; K-block staged here first
  u16* Qst = lds + 9216;       // [c8][64][8]
  u16* Vst = lds + 13312;      // [d][ch^][8] swizzled (contraction = q)
  const int tid = threadIdx.x, w = tid>>6, lane = tid&63;
  const int quad = lane>>4, cl = lane&15;
  const int bh = blockIdx.x, k0 = blockIdx.y*128;   // XCD = bh % 8
  const u16* Kh  = Kc  + (size_t)bh*65536;
  const u16* Qh  = Q   + (size_t)bh*65536;
  const u16* Vth = V2t + (size_t)bh*65536;

  #pragma unroll
  for(int i=0;i<2;i++){
    int slot = i*512 + tid;
    int c = slot >> 7, r = slot & 127;
    gld16(Kh + (size_t)(k0 + r)*64 + c*8, Pl + slot*8);
  }
  __syncthreads();
  bf16x8 kb[2];
  #pragma unroll
  for(int kk=0;kk<2;kk++)
    kb[kk] = *(const bf16x8*)(Pl + ((kk*4+quad)*128 + w*16 + cl)*8);
  __syncthreads();

  f32x4 oacc[4];
  #pragma unroll
  for(int dt=0;dt<4;dt++){ f32x4 z = {0.f,0.f,0.f,0.f}; oacc[dt] = z; }

  for(int qt=0;qt<16;qt++){
    __syncthreads();
    {
      int slot = tid;
      { int c = slot >> 6, r = slot & 63;
        gld16(Qh + (size_t)(qt*64 + r)*64 + c*8, Qst + slot*8); }
      { int d = slot >> 3, ch = slot & 7;
        gld16(Vth + (size_t)d*1024 + qt*64 + (ch^(d&7))*8, Vst + slot*8); }
    }
    __syncthreads();
    f32x4 rv[4];
    #pragma unroll
    for(int mtq=0;mtq<4;mtq++)
      rv[mtq] = *(const f32x4*)(rl_g + bh*1024 + qt*64 + mtq*16 + quad*4);
    #pragma unroll
    for(int mtq=0;mtq<4;mtq++){
      f32x4 s = {0.f,0.f,0.f,0.f};
      #pragma unroll
      for(int kk=0;kk<2;kk++){
        bf16x8 qa = *(const bf16x8*)(Qst + ((kk*4+quad)*64 + mtq*16 + cl)*8);
        s = MFMA(qa, kb[kk], s);
      }
      float p0 = __builtin_amdgcn_exp2f(s[0]*LOG2E)*rv[mtq][0];
      float p1 = __builtin_amdgcn_exp2f(s[1]*LOG2E)*rv[mtq][1];
      float p2 = __builtin_amdgcn_exp2f(s[2]*LOG2E)*rv[mtq][2];
      float p3 = __builtin_amdgcn_exp2f(s[3]*LOG2E)*rv[mtq][3];
      *(u16x4*)(Pl + (w*16 + cl)*72 + mtq*16 + quad*4) = pk4(p0,p1,p2,p3);
    }
    bf16x8 pa[2];
    #pragma unroll
    for(int kk=0;kk<2;kk++)
      pa[kk] = *(const bf16x8*)(Pl + (w*16 + cl)*72 + kk*32 + quad*8);
    #pragma unroll
    for(int dt=0;dt<4;dt++){
      int d = dt*16 + cl;
      #pragma unroll
      for(int kk=0;kk<2;kk++){
        bf16x8 vb = *(const bf16x8*)(Vst + d*64 + (((kk*4+quad)^(d&7))*8));
        oacc[dt] = MFMA(pa[kk], vb, oacc[dt]);
      }
    }
  }
  const int b = bh >> 4, h = bh & 15;
  #pragma unroll
  for(int i=0;i<4;i++){
    int k = k0 + w*16 + quad*4 + i;
    #pragma unroll
    for(int dt=0;dt<4;dt++)
      txtA[(size_t)(b*1024 + k)*1024 + h*64 + dt*16 + cl] = f2bf(oacc[dt][i]);
  }
}

extern "C" void kernel_launch(void* const* d_in, const int* in_sizes, int n_in,
                              void* d_out, int out_size, void* d_ws, size_t ws_size,
                              hipStream_t stream)
{
  const float* vis = (const float*)d_in[0];
  const float* txt = (const float*)d_in[1];
  const float* Wq  = (const float*)d_in[2];
  const float* Wk  = (const float*)d_in[3];
  const float* Wv  = (const float*)d_in[4];
  const float* Wo  = (const float*)d_in[5];
  float* out = (float*)d_out;

  char* ws = (char*)d_ws;
  const size_t MB = 1u << 20;
  u16* vis16 = (u16*)(ws + 0);           // later: visA
  u16* txt16 = (u16*)(ws + 8*MB);        // later: txtA (contiguous with visA for out GEMM)
  u16* Wvis  = (u16*)(ws + 16*MB);       // [WqT | WvT]
  u16* Wtxt  = (u16*)(ws + 20*MB);       // [WkT | WvT]
  u16* Qb    = (u16*)(ws + 24*MB);
  u16* Kb    = (u16*)(ws + 32*MB);
  u16* Vt    = (u16*)(ws + 40*MB);       // V^T  [b][h][d][s]  (from txt proj)
  u16* V2t   = (u16*)(ws + 48*MB);       // V2^T [b][h][d][s]  (from vis proj)
  float* rl_g = (float*)(ws + 56*MB);
  u16* WoT   = (u16*)(ws + 57*MB);
  u16* visA = vis16;  u16* txtA = txt16;

  // 1: cast both inputs + 5 weight transposes
  prep_kernel<<<9472, 256, 0, stream>>>(vis, vis16, txt, txt16,
                                        Wq, Wk, Wv, Wo,
                                        Wvis, Wvis + 1048576, Wtxt, Wtxt + 1048576, WoT);
  // 2: merged projections, 256x128 tiles, 3-deep pipeline; grid.x = m for XCD A-reuse
  proj_gemm_kernel<<<dim3(16,16,2), 512, 0, stream>>>(vis16, txt16, Wvis, Wtxt,
                                                      Qb, V2t, Kb, Vt);
  // 3: attention vis (produces rl); visA overwrites vis16 (dead after projections)
  attn_vis_kernel<<<dim3(64,8), 512, 0, stream>>>(Qb, Kb, Vt, visA, rl_g);
  // 4: attention txt (applies rl in-kernel); txtA overwrites txt16
  attn_txt_kernel<<<dim3(64,8), 512, 0, stream>>>(Kb, Qb, V2t, rl_g, txtA);
  // 5: merged output projection: M=8192 over visA||txtA (contiguous), f32 out
  out_gemm_kernel<<<dim3(32,8), 512, 0, stream>>>(visA, WoT, out);
}

// Round 3
// 223.247 us; speedup vs baseline: 1.2097x; 1.0163x over previous
//
#include <hip/hip_runtime.h>

typedef unsigned short u16;
typedef unsigned int u32;
typedef __bf16 bf16x8 __attribute__((ext_vector_type(8)));
typedef float f32x4 __attribute__((ext_vector_type(4)));
typedef u16 u16x4 __attribute__((ext_vector_type(4)));
typedef __attribute__((address_space(1))) void* as1_t;
typedef __attribute__((address_space(3))) void* as3_t;

#define LOG2E 1.4426950408889634f
#define MFMA(a,b,c) __builtin_amdgcn_mfma_f32_16x16x32_bf16(a,b,c,0,0,0)

__device__ __forceinline__ u16 f2bf(float f){
  u32 u = __float_as_uint(f);
  return (u16)((u + 0x7FFFu + ((u >> 16) & 1u)) >> 16);
}
__device__ __forceinline__ float bf2f(u16 x){
  return __uint_as_float(((u32)x) << 16);
}
#if __has_builtin(__builtin_amdgcn_cvt_pk_bf16_f32)
__device__ __forceinline__ u16x4 pk4(float a, float b, float c, float d){
  auto lo = __builtin_amdgcn_cvt_pk_bf16_f32(a,b);
  auto hi = __builtin_amdgcn_cvt_pk_bf16_f32(c,d);
  union { u16x4 v; u32 w[2]; } u;
  u.w[0] = __builtin_bit_cast(u32, lo);
  u.w[1] = __builtin_bit_cast(u32, hi);
  return u.v;
}
#else
__device__ __forceinline__ u16x4 pk4(float a, float b, float c, float d){
  u16x4 r = { f2bf(a), f2bf(b), f2bf(c), f2bf(d) };
  return r;
}
#endif
__device__ __forceinline__ void gld16(const u16* gp, u16* lp){
  __builtin_amdgcn_global_load_lds((as1_t)(u16*)gp, (as3_t)lp, 16, 0, 0);
}

#define SBAR  __builtin_amdgcn_s_barrier()
#define SCHB  __builtin_amdgcn_sched_barrier(0)
#define SP1   __builtin_amdgcn_s_setprio(1)
#define SP0   __builtin_amdgcn_s_setprio(0)
#define WAITL0 asm volatile("s_waitcnt lgkmcnt(0)" ::: "memory")
#define WAITV6 asm volatile("s_waitcnt vmcnt(6)" ::: "memory")
#define WAITV8 asm volatile("s_waitcnt vmcnt(8)" ::: "memory")

// ---------------- prep: cast both inputs + all 5 weight transposes, ONE launch ----------------
__global__ void prep_kernel(const float* __restrict__ vis, u16* __restrict__ vis16,
                            const float* __restrict__ txt, u16* __restrict__ txt16,
                            const float* __restrict__ Wq, const float* __restrict__ Wk,
                            const float* __restrict__ Wv, const float* __restrict__ Wo,
                            u16* __restrict__ T0, u16* __restrict__ T1,
                            u16* __restrict__ T2, u16* __restrict__ T3,
                            u16* __restrict__ T4){
  int bid = blockIdx.x;
  if(bid < 8192){
    const float* src = (bid < 4096) ? vis : txt;
    u16* dst = (bid < 4096) ? vis16 : txt16;
    int idx = ((bid & 4095)*256 + threadIdx.x)*4;
    float4 v = *(const float4*)(src + idx);
    *(u16x4*)(dst + idx) = pk4(v.x, v.y, v.z, v.w);
    return;
  }
  int rr = bid - 8192;
  int wi = rr >> 8, tile = rr & 255;
  const float* W; u16* WT;
  switch(wi){
    case 0: W = Wq; WT = T0; break;
    case 1: W = Wv; WT = T1; break;
    case 2: W = Wk; WT = T2; break;
    case 3: W = Wv; WT = T3; break;
    default: W = Wo; WT = T4; break;
  }
  __shared__ u16 t[64][65];
  int bn = (tile & 15)*64, bk = (tile >> 4)*64;
  int c = threadIdx.x & 63, r0 = threadIdx.x >> 6;
  #pragma unroll
  for(int j=0;j<64;j+=4){
    int r = r0 + j;
    t[r][c] = f2bf(W[(bk + r)*1024 + bn + c]);
  }
  __syncthreads();
  #pragma unroll
  for(int j=0;j<64;j+=4){
    int r = r0 + j;
    WT[(bn + r)*1024 + bk + c] = t[c][r];
  }
}

// ---------------- merged projection GEMM: 256x256 tile, 2-buf 4-phase, 1 block/CU ------------
// 8 waves 2Mx4N (128x64 per wave: 24 ds_read_b128 per 64 MFMA per K-tile — m201 balance).
// All 8 staging loads of tile t+2 issue in P4 (no ds_reads there; buffer reads proven complete
// by P3's trailing barrier); vmcnt(8) at tile end drains tile t+1 only (issued 4 phases ago).
// grid (16 m, 8 n, 2 z): bid%8 = m%8 -> A-panel sharers co-located per XCD.
__global__ __launch_bounds__(512, 2)
void proj_gemm_kernel(const u16* __restrict__ Avis, const u16* __restrict__ Atxt,
                      const u16* __restrict__ Wvis, const u16* __restrict__ Wtxt,
                      u16* __restrict__ Qb, u16* __restrict__ V2t,
                      u16* __restrict__ Kb, u16* __restrict__ Vt)
{
  const u16 *A, *Bt; u16 *Cn, *Ct;
  if(blockIdx.z == 0){ A = Avis; Bt = Wvis; Cn = Qb; Ct = V2t; }
  else               { A = Atxt; Bt = Wtxt; Cn = Kb; Ct = Vt;  }
  // 128 KiB: buf b at b*32768 (u16): A [256][64] then B [256][64] (+16384).
  __shared__ u16 lds[65536];
  const int tid = threadIdx.x, w = tid >> 6, lane = tid & 63;
  const int quad = lane >> 4, cl = lane & 15;
  const int wr = w >> 2, wc = w & 3;            // 2 M-halves x 4 N-quarters, 128x64 per wave
  const int bm = blockIdx.x*256, bn = blockIdx.y*256;
  const int sx0 = ((quad    ) ^ (cl & 7)) << 3; // kc=0 16B-slot (u16 units)
  const int sx1 = ((quad + 4) ^ (cl & 7)) << 3; // kc=1
  const int arow = ((wr << 7) + cl) << 6;       // (wr*128 + cl)*64
  const int brow = (((wc << 6) + cl) << 6) + 16384;

  f32x4 acc[8][4];
  #pragma unroll
  for(int a=0;a<8;a++)
    #pragma unroll
    for(int b=0;b<4;b++){ f32x4 z = {0.f,0.f,0.f,0.f}; acc[a][b] = z; }
  bf16x8 af[4][2], bfv0[2][2], bfv1[2][2];

  // stage a full 256x64 panel (32 KiB) = 4 gld16/thread; swizzle on GLOBAL src, linear LDS dest
#define STG(G, gbase, dsto, kk) { \
    _Pragma("unroll") \
    for(int ii=0;ii<4;ii++){ \
      int slot_ = ii*512 + tid; int r_ = slot_ >> 3, cs_ = slot_ & 7; \
      gld16((G) + (size_t)((gbase) + r_)*1024 + (kk) + ((cs_ ^ (r_ & 7)) << 3), \
            lds + (dsto) + (ii*512 + (w << 6))*8); } }

#define LDA_(bo, mh) { \
    _Pragma("unroll") \
    for(int q_=0;q_<4;q_++){ \
      int ro_ = (bo) + arow + (((mh)*4 + q_) << 10); \
      af[q_][0] = *(const bf16x8*)(lds + ro_ + sx0); \
      af[q_][1] = *(const bf16x8*)(lds + ro_ + sx1); } }

#define LDB_(bo, nh, bfv) { \
    _Pragma("unroll") \
    for(int j_=0;j_<2;j_++){ \
      int ro_ = (bo) + brow + (((nh)*2 + j_) << 10); \
      bfv[j_][0] = *(const bf16x8*)(lds + ro_ + sx0); \
      bfv[j_][1] = *(const bf16x8*)(lds + ro_ + sx1); } }

#define MM_(mh, bfv, nh) { \
    _Pragma("unroll") \
    for(int q_=0;q_<4;q_++) \
      _Pragma("unroll") \
      for(int j_=0;j_<2;j_++){ \
        acc[(mh)*4+q_][(nh)*2+j_] = MFMA(af[q_][0], bfv[j_][0], acc[(mh)*4+q_][(nh)*2+j_]); \
        acc[(mh)*4+q_][(nh)*2+j_] = MFMA(af[q_][1], bfv[j_][1], acc[(mh)*4+q_][(nh)*2+j_]); } }

  // one K-tile: 4 phases; P4 stages tile t+2 into THIS buffer (reads done) and drains t+1
#define TILE(bufo, ts) { \
    LDA_(bufo, 0); LDB_(bufo, 0, bfv0); \
    SBAR; WAITL0; SCHB; SP1; MM_(0, bfv0, 0); SP0; SBAR; \
    LDB_(bufo, 1, bfv1); \
    SBAR; WAITL0; SCHB; SP1; MM_(0, bfv1, 1); SP0; SBAR; \
    LDA_(bufo, 1); \
    SBAR; WAITL0; SCHB; SP1; MM_(1, bfv1, 1); SP0; SBAR; \
    STG(A , bm, (bufo)        , ts); \
    STG(Bt, bn, (bufo) + 16384, ts); \
    SCHB; SP1; MM_(1, bfv0, 0); SP0; \
    WAITV8; SBAR; }

  // prologue: tile0 -> buf0, tile1 -> buf1; drain tile0 (8 oldest), keep tile1 in flight
  STG(A , bm, 0,     0);  STG(Bt, bn, 16384, 0);
  STG(A , bm, 32768, 64); STG(Bt, bn, 32768+16384, 64);
  WAITV8; SBAR;

  for(int tt=0; tt<8; tt++){
    const int t0 = 2*tt;
    TILE(0,     ((t0+2)&15) << 6);
    TILE(32768, ((t0+3)&15) << 6);
  }
#undef STG
#undef LDA_
#undef LDB_
#undef MM_
#undef TILE

  if(bn < 1024){
    #pragma unroll
    for(int mf=0; mf<8; mf++){
      int m0 = bm + wr*128 + mf*16 + quad*4;
      #pragma unroll
      for(int nf=0; nf<4; nf++){
        int n = bn + wc*64 + nf*16 + cl;
        int h = n >> 6, d = n & 63;
        #pragma unroll
        for(int i2=0;i2<4;i2++){
          int m = m0 + i2; int b = m >> 10, s = m & 1023;
          Cn[(((size_t)(b*16 + h)*1024 + s) << 6) + d] = f2bf(acc[mf][nf][i2]);
        }
      }
    }
  } else {
    #pragma unroll
    for(int mf=0; mf<8; mf++){
      int m0 = bm + wr*128 + mf*16 + quad*4;
      int b = m0 >> 10, s = m0 & 1023;
      #pragma unroll
      for(int nf=0; nf<4; nf++){
        int nn = bn - 1024 + wc*64 + nf*16 + cl;
        int h = nn >> 6, d = nn & 63;
        *(u16x4*)(Ct + (((size_t)(b*16 + h)*64 + d) << 10) + s) =
            pk4(acc[mf][nf][0], acc[mf][nf][1], acc[mf][nf][2], acc[mf][nf][3]);
      }
    }
  }
}

// ============ out_gemm body: 256x128 (BK=64) 3-deep pipelined (round-2 structure) ============
__device__ __forceinline__ void gemm_pipe(const u16* __restrict__ A,
                                          const u16* __restrict__ Bt,
                                          int bm, int bn,
                                          u16* __restrict__ lds,
                                          f32x4 (&acc)[4][4],
                                          int tid, int w, int quad, int cl,
                                          int wr, int wc)
{
  const int sx0 = ((quad    ) ^ (cl & 7)) << 3;
  const int sx1 = ((quad + 4) ^ (cl & 7)) << 3;
  const int arow = ((wr << 6) + cl) << 6;
  const int brow = (((wc << 6) + cl) << 6) + 16384;
  bf16x8 af[4][2], bfv[2][2];

#define STAGE128(G, gbase, dsto, kk) { \
    _Pragma("unroll") \
    for(int ii=0;ii<2;ii++){ \
      int slot_ = ii*512 + tid; int r_ = slot_ >> 3, cs_ = slot_ & 7; \
      gld16((G) + (size_t)((gbase) + r_)*1024 + (kk) + ((cs_ ^ (r_ & 7)) << 3), \
            lds + (dsto) + (ii*512 + (w << 6))*8); } }

#define LDA_(bo) { \
    _Pragma("unroll") \
    for(int m_=0;m_<4;m_++){ \
      int ro_ = (bo) + arow + (m_ << 10); \
      af[m_][0] = *(const bf16x8*)(lds + ro_ + sx0); \
      af[m_][1] = *(const bf16x8*)(lds + ro_ + sx1); } }

#define LDB_(bo, nh) { \
    _Pragma("unroll") \
    for(int j_=0;j_<2;j_++){ \
      int ro_ = (bo) + brow + (((nh)*2 + j_) << 10); \
      bfv[j_][0] = *(const bf16x8*)(lds + ro_ + sx0); \
      bfv[j_][1] = *(const bf16x8*)(lds + ro_ + sx1); } }

#define MM_(nh) { \
    _Pragma("unroll") \
    for(int m_=0;m_<4;m_++) \
      _Pragma("unroll") \
      for(int j_=0;j_<2;j_++){ \
        acc[m_][(nh)*2+j_] = MFMA(af[m_][0], bfv[j_][0], acc[m_][(nh)*2+j_]); \
        acc[m_][(nh)*2+j_] = MFMA(af[m_][1], bfv[j_][1], acc[m_][(nh)*2+j_]); } }

  STAGE128(A , bm      , 0,          0);
  STAGE128(A , bm + 128, 8192,       0);
  STAGE128(Bt, bn      , 16384,      0);
  STAGE128(A , bm      , 24576,      64);
  STAGE128(A , bm + 128, 24576+8192, 64);
  STAGE128(Bt, bn      , 24576+16384,64);
  WAITV6; SBAR;

  #pragma unroll 2
  for(int t=0;t<16;t++){
    const int c  = (t % 3) * 24576;
    const int n2 = ((t+2) % 3) * 24576;
    const int ts = ((t+2) & 15) << 6;
    LDA_(c); LDB_(c, 0);
    STAGE128(A, bm      , n2,        ts);
    STAGE128(A, bm + 128, n2 + 8192, ts);
    SBAR; WAITL0; SCHB;
    SP1; MM_(0); SP0;
    SBAR;
    LDB_(c, 1);
    STAGE128(Bt, bn, n2 + 16384, ts);
    SBAR; WAITL0; SCHB;
    SP1; MM_(1); SP0;
    WAITV6;
    SBAR;
  }
#undef STAGE128
#undef LDA_
#undef LDB_
#undef MM_
}

// ---------------- output GEMM: out[8192 x 1024] f32 = A * WoT, 256x128 3-deep pipeline -------
__global__ __launch_bounds__(512, 2)
void out_gemm_kernel(const u16* __restrict__ A, const u16* __restrict__ Bt,
                     float* __restrict__ Cf)
{
  __shared__ u16 lds[73728];
  const int tid = threadIdx.x, w = tid >> 6, lane = tid & 63;
  const int quad = lane >> 4, cl = lane & 15;
  const int wr = w >> 1, wc = w & 1;
  const int bm = blockIdx.x*256, bn = blockIdx.y*128;

  f32x4 acc[4][4];
  #pragma unroll
  for(int a=0;a<4;a++)
    #pragma unroll
    for(int b=0;b<4;b++){ f32x4 z = {0.f,0.f,0.f,0.f}; acc[a][b] = z; }

  gemm_pipe(A, Bt, bm, bn, lds, acc, tid, w, quad, cl, wr, wc);

  #pragma unroll
  for(int mf=0; mf<4; mf++)
    #pragma unroll
    for(int nf=0; nf<4; nf++)
      #pragma unroll
      for(int i=0;i<4;i++){
        int m = bm + wr*64 + mf*16 + quad*4 + i;
        int n = bn + wc*64 + nf*16 + cl;
        Cf[(size_t)m*1024 + n] = acc[mf][nf][i];
      }
}

// ---------------- attention (vis): 8 waves x 16 q-rows; grid x=bh (XCD-grouped K/V) ----------------
__global__ __launch_bounds__(512, 4)
void attn_vis_kernel(const u16* __restrict__ Q, const u16* __restrict__ Kc,
                     const u16* __restrict__ Vt, u16* __restrict__ visA,
                     float* __restrict__ rl_g)
{
  __shared__ u16 lds[17408];   // 34816 B
  u16* Pl  = lds;              // P[q=128][72]; Q staged here first ([c8][128][8]=8192)
  u16* Kst = lds + 9216;       // [c8][64][8] = 4096 u16
  u16* Vst = lds + 13312;      // [d=64][ch^][8] swizzled = 4096 u16
  const int tid = threadIdx.x, w = tid>>6, lane = tid&63;
  const int quad = lane>>4, cl = lane&15;
  const int bh = blockIdx.x, q0 = blockIdx.y*128;   // XCD = bh % 8
  const u16* Qh  = Q  + (size_t)bh*65536;
  const u16* Kh  = Kc + (size_t)bh*65536;
  const u16* Vth = Vt + (size_t)bh*65536;

  #pragma unroll
  for(int i=0;i<2;i++){
    int slot = i*512 + tid;
    int c = slot >> 7, r = slot & 127;
    gld16(Qh + (size_t)(q0 + r)*64 + c*8, Pl + slot*8);
  }
  __syncthreads();
  bf16x8 qf[2];
  #pragma unroll
  for(int kk=0;kk<2;kk++)
    qf[kk] = *(const bf16x8*)(Pl + ((kk*4+quad)*128 + w*16 + cl)*8);
  __syncthreads();   // Pl now becomes the P buffer

  float lrun = 0.f;
  f32x4 oacc[4];
  #pragma unroll
  for(int dt=0;dt<4;dt++){ f32x4 z = {0.f,0.f,0.f,0.f}; oacc[dt] = z; }

  for(int kt=0;kt<16;kt++){
    __syncthreads();
    {
      int slot = tid;
      { int c = slot >> 6, r = slot & 63;
        gld16(Kh + (size_t)(kt*64 + r)*64 + c*8, Kst + slot*8); }
      { int d = slot >> 3, ch = slot & 7;
        gld16(Vth + (size_t)d*1024 + kt*64 + (ch^(d&7))*8, Vst + slot*8); }
    }
    __syncthreads();
    #pragma unroll
    for(int mtk=0;mtk<4;mtk++){
      f32x4 s = {0.f,0.f,0.f,0.f};
      #pragma unroll
      for(int kk=0;kk<2;kk++){
        bf16x8 ka = *(const bf16x8*)(Kst + ((kk*4+quad)*64 + mtk*16 + cl)*8);
        s = MFMA(ka, qf[kk], s);
      }
      float p0 = __builtin_amdgcn_exp2f(s[0]*LOG2E);
      float p1 = __builtin_amdgcn_exp2f(s[1]*LOG2E);
      float p2 = __builtin_amdgcn_exp2f(s[2]*LOG2E);
      float p3 = __builtin_amdgcn_exp2f(s[3]*LOG2E);
      lrun += (p0+p1)+(p2+p3);
      *(u16x4*)(Pl + (w*16 + cl)*72 + mtk*16 + quad*4) = pk4(p0,p1,p2,p3);
    }
    bf16x8 pa[2];
    #pragma unroll
    for(int kk=0;kk<2;kk++)
      pa[kk] = *(const bf16x8*)(Pl + (w*16 + cl)*72 + kk*32 + quad*8);
    #pragma unroll
    for(int dt=0;dt<4;dt++){
      int d = dt*16 + cl;
      #pragma unroll
      for(int kk=0;kk<2;kk++){
        bf16x8 vb = *(const bf16x8*)(Vst + d*64 + (((kk*4+quad)^(d&7))*8));
        oacc[dt] = MFMA(pa[kk], vb, oacc[dt]);
      }
    }
  }
  lrun += __shfl_xor(lrun, 16, 64);
  lrun += __shfl_xor(lrun, 32, 64);
  float rl = 1.f/lrun;
  if(quad == 0) rl_g[bh*1024 + q0 + w*16 + cl] = rl;
  const int b = bh >> 4, h = bh & 15;
  #pragma unroll
  for(int i=0;i<4;i++){
    float rr = __shfl(rl, quad*4 + i, 16);
    int q = q0 + w*16 + quad*4 + i;
    #pragma unroll
    for(int dt=0;dt<4;dt++)
      visA[(size_t)(b*1024 + q)*1024 + h*64 + dt*16 + cl] = f2bf(oacc[dt][i]*rr);
  }
}

// ---------------- attention (txt): 8 waves x 16 k-rows; grid x=bh; rl applied in-kernel ----------
__global__ __launch_bounds__(512, 4)
void attn_txt_kernel(const u16* __restrict__ Kc, const u16* __restrict__ Q,
                     const u16* __restrict__ V2t, const float* __restrict__ rl_g,
                     u16* __restrict__ txtA)
{
  __shared__ u16 lds[17408];
  u16* Pl  = lds;              // P^T[k=128][72]; K-block staged here first
  u16* Qst = lds + 9216;       // [c8][64][8]
  u16* Vst = lds + 13312;      // [d][ch^][8] swizzled (contraction = q)
  const int tid = threadIdx.x, w = tid>>6, lane = tid&63;
  const int quad = lane>>4, cl = lane&15;
  const int bh = blockIdx.x, k0 = blockIdx.y*128;   // XCD = bh % 8
  const u16* Kh  = Kc  + (size_t)bh*65536;
  const u16* Qh  = Q   + (size_t)bh*65536;
  const u16* Vth = V2t + (size_t)bh*65536;

  #pragma unroll
  for(int i=0;i<2;i++){
    int slot = i*512 + tid;
    int c = slot >> 7, r = slot & 127;
    gld16(Kh + (size_t)(k0 + r)*64 + c*8, Pl + slot*8);
  }
  __syncthreads();
  bf16x8 kb[2];
  #pragma unroll
  for(int kk=0;kk<2;kk++)
    kb[kk] = *(const bf16x8*)(Pl + ((kk*4+quad)*128 + w*16 + cl)*8);
  __syncthreads();

  f32x4 oacc[4];
  #pragma unroll
  for(int dt=0;dt<4;dt++){ f32x4 z = {0.f,0.f,0.f,0.f}; oacc[dt] = z; }

  for(int qt=0;qt<16;qt++){
    __syncthreads();
    {
      int slot = tid;
      { int c = slot >> 6, r = slot & 63;
        gld16(Qh + (size_t)(qt*64 + r)*64 + c*8, Qst + slot*8); }
      { int d = slot >> 3, ch = slot & 7;
        gld16(Vth + (size_t)d*1024 + qt*64 + (ch^(d&7))*8, Vst + slot*8); }
    }
    __syncthreads();
    f32x4 rv[4];
    #pragma unroll
    for(int mtq=0;mtq<4;mtq++)
      rv[mtq] = *(const f32x4*)(rl_g + bh*1024 + qt*64 + mtq*16 + quad*4);
    #pragma unroll
    for(int mtq=0;mtq<4;mtq++){
      f32x4 s = {0.f,0.f,0.f,0.f};
      #pragma unroll
      for(int kk=0;kk<2;kk++){
        bf16x8 qa = *(const bf16x8*)(Qst + ((kk*4+quad)*64 + mtq*16 + cl)*8);
        s = MFMA(qa, kb[kk], s);
      }
      float p0 = __builtin_amdgcn_exp2f(s[0]*LOG2E)*rv[mtq][0];
      float p1 = __builtin_amdgcn_exp2f(s[1]*LOG2E)*rv[mtq][1];
      float p2 = __builtin_amdgcn_exp2f(s[2]*LOG2E)*rv[mtq][2];
      float p3 = __builtin_amdgcn_exp2f(s[3]*LOG2E)*rv[mtq][3];
      *(u16x4*)(Pl + (w*16 + cl)*72 + mtq*16 + quad*4) = pk4(p0,p1,p2,p3);
    }
    bf16x8 pa[2];
    #pragma unroll
    for(int kk=0;kk<2;kk++)
      pa[kk] = *(const bf16x8*)(Pl + (w*16 + cl)*72 + kk*32 + quad*8);
    #pragma unroll
    for(int dt=0;dt<4;dt++){
      int d = dt*16 + cl;
      #pragma unroll
      for(int kk=0;kk<2;kk++){
        bf16x8 vb = *(const bf16x8*)(Vst + d*64 + (((kk*4+quad)^(d&7))*8));
        oacc[dt] = MFMA(pa[kk], vb, oacc[dt]);
      }
    }
  }
  const int b = bh >> 4, h = bh & 15;
  #pragma unroll
  for(int i=0;i<4;i++){
    int k = k0 + w*16 + quad*4 + i;
    #pragma unroll
    for(int dt=0;dt<4;dt++)
      txtA[(size_t)(b*1024 + k)*1024 + h*64 + dt*16 + cl] = f2bf(oacc[dt][i]);
  }
}

extern "C" void kernel_launch(void* const* d_in, const int* in_sizes, int n_in,
                              void* d_out, int out_size, void* d_ws, size_t ws_size,
                              hipStream_t stream)
{
  const float* vis = (const float*)d_in[0];
  const float* txt = (const float*)d_in[1];
  const float* Wq  = (const float*)d_in[2];
  const float* Wk  = (const float*)d_in[3];
  const float* Wv  = (const float*)d_in[4];
  const float* Wo  = (const float*)d_in[5];
  float* out = (float*)d_out;

  char* ws = (char*)d_ws;
  const size_t MB = 1u << 20;
  u16* vis16 = (u16*)(ws + 0);           // later: visA
  u16* txt16 = (u16*)(ws + 8*MB);        // later: txtA (contiguous with visA for out GEMM)
  u16* Wvis  = (u16*)(ws + 16*MB);       // [WqT | WvT]
  u16* Wtxt  = (u16*)(ws + 20*MB);       // [WkT | WvT]
  u16* Qb    = (u16*)(ws + 24*MB);
  u16* Kb    = (u16*)(ws + 32*MB);
  u16* Vt    = (u16*)(ws + 40*MB);       // V^T  [b][h][d][s]  (from txt proj)
  u16* V2t   = (u16*)(ws + 48*MB);       // V2^T [b][h][d][s]  (from vis proj)
  float* rl_g = (float*)(ws + 56*MB);
  u16* WoT   = (u16*)(ws + 57*MB);
  u16* visA = vis16;  u16* txtA = txt16;

  // 1: cast both inputs + 5 weight transposes
  prep_kernel<<<9472, 256, 0, stream>>>(vis, vis16, txt, txt16,
                                        Wq, Wk, Wv, Wo,
                                        Wvis, Wvis + 1048576, Wtxt, Wtxt + 1048576, WoT);
  // 2: merged projections, 256x256 tiles, 2-buf 4-phase, 256 blocks (1/CU)
  proj_gemm_kernel<<<dim3(16,8,2), 512, 0, stream>>>(vis16, txt16, Wvis, Wtxt,
                                                     Qb, V2t, Kb, Vt);
  // 3: attention vis (produces rl); visA overwrites vis16 (dead after projections)
  attn_vis_kernel<<<dim3(64,8), 512, 0, stream>>>(Qb, Kb, Vt, visA, rl_g);
  // 4: attention txt (applies rl in-kernel); txtA overwrites txt16
  attn_txt_kernel<<<dim3(64,8), 512, 0, stream>>>(Kb, Qb, V2t, rl_g, txtA);
  // 5: merged output projection: M=8192 over visA||txtA (contiguous), f32 out
  out_gemm_kernel<<<dim3(32,8), 512, 0, stream>>>(visA, WoT, out);
}